// Round 1
// baseline (2650.509 us; speedup 1.0000x reference)
//
#include <hip/hip_runtime.h>
#include <cstdint>
#include <cstddef>

#define F_IN   128
#define HC     256   // H0*C0 = 256 = H1*C1
#define SLOPE  0.2f

// ---------- float <-> order-preserving uint (for atomicMax on floats) ----------
__device__ __forceinline__ unsigned f2ord(float v) {
    unsigned b = __float_as_uint(v);
    return (b & 0x80000000u) ? ~b : (b | 0x80000000u);
}
__device__ __forceinline__ float ord2f(unsigned u) {
    return __uint_as_float((u & 0x80000000u) ? (u & 0x7FFFFFFFu) : ~u);
}

// ---------------- tiled fp32 GEMM: C[M,Nc] = A[M,K] @ B[K,Nc] ----------------
// BM=64 BN=64 BK=16, 256 threads, 4x4 per thread. Nc multiple of 64, K mult of 16.
__global__ __launch_bounds__(256) void gemm64(
    const float* __restrict__ A, const float* __restrict__ B, float* __restrict__ C,
    int M, int Nc, int K) {
    __shared__ __align__(16) float As[16][65];
    __shared__ __align__(16) float Bs[16][65];
    int t  = threadIdx.x;
    int nb = Nc >> 6;
    int bx = blockIdx.x % nb;
    int by = blockIdx.x / nb;
    int tx = t & 15, ty = t >> 4;
    int row0 = by * 64, col0 = bx * 64;
    float acc[4][4] = {};
    for (int k0 = 0; k0 < K; k0 += 16) {
        // A tile: 64 rows x 16 k
        int r  = t >> 2, kq = (t & 3) * 4;
        int gr = row0 + r;
        float4 av = make_float4(0.f, 0.f, 0.f, 0.f);
        if (gr < M) av = *(const float4*)(A + (size_t)gr * K + k0 + kq);
        As[kq + 0][r] = av.x; As[kq + 1][r] = av.y;
        As[kq + 2][r] = av.z; As[kq + 3][r] = av.w;
        // B tile: 16 k x 64 cols
        int br = t >> 4, bc = (t & 15) * 4;
        float4 bv = *(const float4*)(B + (size_t)(k0 + br) * Nc + col0 + bc);
        Bs[br][bc + 0] = bv.x; Bs[br][bc + 1] = bv.y;
        Bs[br][bc + 2] = bv.z; Bs[br][bc + 3] = bv.w;
        __syncthreads();
        #pragma unroll
        for (int kk = 0; kk < 16; ++kk) {
            float a0 = As[kk][ty * 4 + 0], a1 = As[kk][ty * 4 + 1];
            float a2 = As[kk][ty * 4 + 2], a3 = As[kk][ty * 4 + 3];
            float b0 = Bs[kk][tx * 4 + 0], b1 = Bs[kk][tx * 4 + 1];
            float b2 = Bs[kk][tx * 4 + 2], b3 = Bs[kk][tx * 4 + 3];
            acc[0][0] += a0 * b0; acc[0][1] += a0 * b1; acc[0][2] += a0 * b2; acc[0][3] += a0 * b3;
            acc[1][0] += a1 * b0; acc[1][1] += a1 * b1; acc[1][2] += a1 * b2; acc[1][3] += a1 * b3;
            acc[2][0] += a2 * b0; acc[2][1] += a2 * b1; acc[2][2] += a2 * b2; acc[2][3] += a2 * b3;
            acc[3][0] += a3 * b0; acc[3][1] += a3 * b1; acc[3][2] += a3 * b2; acc[3][3] += a3 * b3;
        }
        __syncthreads();
    }
    #pragma unroll
    for (int i = 0; i < 4; ++i) {
        int gr = row0 + ty * 4 + i;
        if (gr < M) {
            #pragma unroll
            for (int j = 0; j < 4; ++j)
                C[(size_t)gr * Nc + col0 + tx * 4 + j] = acc[i][j];
        }
    }
}

// ---------------- alpha dot products ----------------
// layer0: 4 heads x 64; wave per node, lane=c within head.
__global__ void alphas0_k(const float* __restrict__ h0, const float* __restrict__ a_src,
                          const float* __restrict__ a_dst, float* __restrict__ asrc,
                          float* __restrict__ adst, int N) {
    int gid = blockIdx.x * blockDim.x + threadIdx.x;
    int n = gid >> 6, lane = gid & 63;
    if (n >= N) return;
    #pragma unroll
    for (int h = 0; h < 4; ++h) {
        float v  = h0[(size_t)n * 256 + h * 64 + lane];
        float s1 = v * a_src[h * 64 + lane];
        float s2 = v * a_dst[h * 64 + lane];
        #pragma unroll
        for (int off = 32; off; off >>= 1) {
            s1 += __shfl_down(s1, off);
            s2 += __shfl_down(s2, off);
        }
        if (lane == 0) { asrc[n * 4 + h] = s1; adst[n * 4 + h] = s2; }
    }
}

// layer1: 1 head x 256; wave per node, 4 strided chunks.
__global__ void alphas1_k(const float* __restrict__ h1, const float* __restrict__ a_src,
                          const float* __restrict__ a_dst, float* __restrict__ asrc,
                          float* __restrict__ adst, int N) {
    int gid = blockIdx.x * blockDim.x + threadIdx.x;
    int n = gid >> 6, lane = gid & 63;
    if (n >= N) return;
    float s1 = 0.f, s2 = 0.f;
    #pragma unroll
    for (int k = 0; k < 4; ++k) {
        float v = h1[(size_t)n * 256 + k * 64 + lane];
        s1 += v * a_src[k * 64 + lane];
        s2 += v * a_dst[k * 64 + lane];
    }
    #pragma unroll
    for (int off = 32; off; off >>= 1) {
        s1 += __shfl_down(s1, off);
        s2 += __shfl_down(s2, off);
    }
    if (lane == 0) { asrc[n] = s1; adst[n] = s2; }
}

// ---------------- edge pass A: scores + segment max ----------------
__global__ void edge_scores0(const int* __restrict__ ei, const float* __restrict__ asrc,
                             const float* __restrict__ adst, float* __restrict__ escore,
                             unsigned* __restrict__ emaxu, int E, int N) {
    int e = blockIdx.x * blockDim.x + threadIdx.x;
    if (e >= E + N) return;
    int s, d; bool valid;
    if (e < E) { s = ei[e]; d = ei[E + e]; valid = (s != d); }
    else       { s = d = e - E; valid = true; }
    #pragma unroll
    for (int h = 0; h < 4; ++h) {
        float v = asrc[s * 4 + h] + adst[d * 4 + h];
        v = v >= 0.f ? v : SLOPE * v;
        if (!valid) v = -1e9f;
        escore[(size_t)e * 4 + h] = v;
        atomicMax(&emaxu[d * 4 + h], f2ord(v));
    }
}

__global__ void edge_scores1(const int* __restrict__ ei, const float* __restrict__ asrc,
                             const float* __restrict__ adst, float* __restrict__ escore,
                             unsigned* __restrict__ emaxu, int E, int N) {
    int e = blockIdx.x * blockDim.x + threadIdx.x;
    if (e >= E + N) return;
    int s, d; bool valid;
    if (e < E) { s = ei[e]; d = ei[E + e]; valid = (s != d); }
    else       { s = d = e - E; valid = true; }
    float v = asrc[s] + adst[d];
    v = v >= 0.f ? v : SLOPE * v;
    if (!valid) v = -1e9f;
    escore[e] = v;
    atomicMax(&emaxu[d], f2ord(v));
}

// ---------------- edge pass B: exp weights + scatter aggregate ----------------
// layer0: wave per edge; lane = c within head; loop 4 heads.
__global__ void edge_agg0(const int* __restrict__ ei, const float* __restrict__ h0,
                          const float* __restrict__ escore, const unsigned* __restrict__ emaxu,
                          float* __restrict__ denom, float* __restrict__ agg, int E, int N) {
    int gid = blockIdx.x * blockDim.x + threadIdx.x;
    int e = gid >> 6, lane = gid & 63;
    if (e >= E + N) return;
    int s, d;
    if (e < E) { s = ei[e]; d = ei[E + e]; }
    else       { s = d = e - E; }
    #pragma unroll
    for (int h = 0; h < 4; ++h) {
        float w = __expf(escore[(size_t)e * 4 + h] - ord2f(emaxu[d * 4 + h]));
        if (lane == 0) atomicAdd(&denom[d * 4 + h], w);
        if (w != 0.f)
            atomicAdd(&agg[(size_t)d * 256 + h * 64 + lane],
                      w * h0[(size_t)s * 256 + h * 64 + lane]);
    }
}

// layer1: block(256) per edge.
__global__ __launch_bounds__(256) void edge_agg1(
    const int* __restrict__ ei, const float* __restrict__ h1,
    const float* __restrict__ escore, const unsigned* __restrict__ emaxu,
    float* __restrict__ denom, float* __restrict__ agg, int E, int N) {
    int e = blockIdx.x, c = threadIdx.x;
    int s, d;
    if (e < E) { s = ei[e]; d = ei[E + e]; }
    else       { s = d = e - E; }
    float w = __expf(escore[e] - ord2f(emaxu[d]));
    if (w != 0.f)
        atomicAdd(&agg[(size_t)d * 256 + c], w * h1[(size_t)s * 256 + c]);
    if (c == 0) atomicAdd(&denom[d], w);
}

// ---------------- normalize + bias + relu ----------------
__global__ void norm0_k(float* __restrict__ agg, const float* __restrict__ denom,
                        const float* __restrict__ b, int N) {
    int i = blockIdx.x * blockDim.x + threadIdx.x;
    if (i >= N * 256) return;
    int n = i >> 8, c = i & 255, h = c >> 6;
    float v = agg[i] / denom[n * 4 + h] + b[c];
    agg[i] = v > 0.f ? v : 0.f;
}

__global__ void norm1_k(float* __restrict__ agg, const float* __restrict__ denom,
                        const float* __restrict__ b, int N) {
    int i = blockIdx.x * blockDim.x + threadIdx.x;
    if (i >= N * 256) return;
    int n = i >> 8, c = i & 255;
    float v = agg[i] / denom[n] + b[c];
    agg[i] = v > 0.f ? v : 0.f;
}

// ---------------- fused MLP: 256 -> 512 -> 1024 -> 10 -> softmax ----------------
// 16 nodes per block, 256 threads. All intermediates in LDS; weights from L2.
__global__ __launch_bounds__(256) void fused_mlp(
    const float* __restrict__ m0,
    const float* __restrict__ lw1, const float* __restrict__ lb1,
    const float* __restrict__ lw2, const float* __restrict__ lb2,
    const float* __restrict__ lw3, const float* __restrict__ lb3,
    float* __restrict__ out, int N) {
    __shared__ __align__(16) float sm0[16][256];
    __shared__ __align__(16) float sm1[16][512];
    __shared__ __align__(16) float sm2[16][256];
    __shared__ float slog[16][10];
    int t  = threadIdx.x;
    int nb = blockIdx.x * 16;
    // load input tile
    #pragma unroll
    for (int i = 0; i < 16; ++i) {
        int idx = t + i * 256;
        int n = idx >> 8, c = idx & 255;
        int gn = nb + n;
        sm0[n][c] = (gn < N) ? m0[(size_t)gn * 256 + c] : 0.f;
    }
    if (t < 160) slog[t / 10][t % 10] = 0.f;
    __syncthreads();

    // ---- layer 1: 256 -> 512, each thread owns 2 output cols (j0=2t, 2t+1) ----
    {
        float acc0[16] = {}, acc1[16] = {};
        const float2* w1p = (const float2*)lw1;
        for (int i = 0; i < 256; i += 4) {
            float2 w[4];
            #pragma unroll
            for (int u = 0; u < 4; ++u) w[u] = w1p[(size_t)(i + u) * 256 + t];
            #pragma unroll
            for (int n = 0; n < 16; ++n) {
                float4 x = *(const float4*)&sm0[n][i];
                acc0[n] += x.x * w[0].x + x.y * w[1].x + x.z * w[2].x + x.w * w[3].x;
                acc1[n] += x.x * w[0].y + x.y * w[1].y + x.z * w[2].y + x.w * w[3].y;
            }
        }
        float bv0 = lb1[2 * t], bv1 = lb1[2 * t + 1];
        #pragma unroll
        for (int n = 0; n < 16; ++n) {
            float v0 = acc0[n] + bv0, v1 = acc1[n] + bv1;
            sm1[n][2 * t]     = v0 > 0.f ? v0 : 0.f;
            sm1[n][2 * t + 1] = v1 > 0.f ? v1 : 0.f;
        }
    }
    __syncthreads();

    // ---- layer 2 (512 -> 1024) in 4 chunks of 256 cols, fused with layer-3 accumulation ----
    for (int ch = 0; ch < 4; ++ch) {
        int j  = t & 127, g = t >> 7;         // g selects node half
        int j2 = ch * 256 + j;
        float accA[8] = {}, accB[8] = {};
        for (int i = 0; i < 512; i += 4) {
            float wA[4], wB[4];
            #pragma unroll
            for (int u = 0; u < 4; ++u) {
                wA[u] = lw2[(size_t)(i + u) * 1024 + j2];
                wB[u] = lw2[(size_t)(i + u) * 1024 + j2 + 128];
            }
            #pragma unroll
            for (int q = 0; q < 8; ++q) {
                float4 x = *(const float4*)&sm1[g * 8 + q][i];
                accA[q] += x.x * wA[0] + x.y * wA[1] + x.z * wA[2] + x.w * wA[3];
                accB[q] += x.x * wB[0] + x.y * wB[1] + x.z * wB[2] + x.w * wB[3];
            }
        }
        float bA = lb2[j2], bB = lb2[j2 + 128];
        #pragma unroll
        for (int q = 0; q < 8; ++q) {
            float vA = accA[q] + bA, vB = accB[q] + bB;
            sm2[g * 8 + q][j]       = vA > 0.f ? vA : 0.f;
            sm2[g * 8 + q][j + 128] = vB > 0.f ? vB : 0.f;
        }
        __syncthreads();
        if (t < 160) {
            int n = t / 10, k = t % 10;
            float s = 0.f;
            for (int jj = 0; jj < 256; ++jj)
                s += sm2[n][jj] * lw3[(size_t)(ch * 256 + jj) * 10 + k];
            slog[n][k] += s;
        }
        __syncthreads();
    }

    // ---- bias + relu + softmax ----
    if (t < 16 && nb + t < N) {
        float lg[10], m = -1e30f;
        #pragma unroll
        for (int k = 0; k < 10; ++k) {
            float v = slog[t][k] + lb3[k];
            v = v > 0.f ? v : 0.f;
            lg[k] = v;
            if (v > m) m = v;
        }
        float ssum = 0.f;
        #pragma unroll
        for (int k = 0; k < 10; ++k) { lg[k] = __expf(lg[k] - m); ssum += lg[k]; }
        float inv = 1.f / ssum;
        #pragma unroll
        for (int k = 0; k < 10; ++k) out[(size_t)(nb + t) * 10 + k] = lg[k] * inv;
    }
}

// ---------------------------------------------------------------------------
extern "C" void kernel_launch(void* const* d_in, const int* in_sizes, int n_in,
                              void* d_out, int out_size, void* d_ws, size_t ws_size,
                              hipStream_t stream) {
    const float* x       = (const float*)d_in[0];
    const int*   ei      = (const int*)  d_in[1];
    const float* W0      = (const float*)d_in[2];
    const float* a_src0  = (const float*)d_in[3];
    const float* a_dst0  = (const float*)d_in[4];
    const float* b0      = (const float*)d_in[5];
    const float* W1      = (const float*)d_in[6];
    const float* a_src1  = (const float*)d_in[7];
    const float* a_dst1  = (const float*)d_in[8];
    const float* b1      = (const float*)d_in[9];
    const float* lw1     = (const float*)d_in[10];
    const float* lb1     = (const float*)d_in[11];
    const float* lw2     = (const float*)d_in[12];
    const float* lb2     = (const float*)d_in[13];
    const float* lw3     = (const float*)d_in[14];
    const float* lb3     = (const float*)d_in[15];
    float*       out     = (float*)d_out;

    const int N  = in_sizes[0] / F_IN;   // 50000
    const int E  = in_sizes[1] / 2;      // 400000
    const int ET = E + N;

    // workspace layout (floats)
    float* ws     = (float*)d_ws;
    size_t szH    = (size_t)N * 256;
    float* bufH   = ws;                       // h0, then h1
    float* bufG   = ws + szH;                 // agg0->x1, then agg1->m0
    float* asrc   = ws + 2 * szH;             // N*4
    float* adst   = asrc + (size_t)N * 4;
    unsigned* emaxu = (unsigned*)(adst + (size_t)N * 4);
    float* denom  = (float*)emaxu + (size_t)N * 4;
    float* escore = denom + (size_t)N * 4;    // ET*4

    const int TB = 256;

    // ===== GAT layer 0 =====
    // h0 = x @ W0
    gemm64<<<dim3((256 / 64) * ((N + 63) / 64)), TB, 0, stream>>>(x, W0, bufH, N, 256, F_IN);
    alphas0_k<<<(N * 64 + TB - 1) / TB, TB, 0, stream>>>(bufH, a_src0, a_dst0, asrc, adst, N);
    hipMemsetAsync(emaxu, 0, (size_t)N * 4 * sizeof(unsigned), stream);
    hipMemsetAsync(denom, 0, (size_t)N * 4 * sizeof(float), stream);
    hipMemsetAsync(bufG, 0, szH * sizeof(float), stream);
    edge_scores0<<<(ET + TB - 1) / TB, TB, 0, stream>>>(ei, asrc, adst, escore, emaxu, E, N);
    edge_agg0<<<((size_t)ET * 64 + TB - 1) / TB, TB, 0, stream>>>(ei, bufH, escore, emaxu, denom, bufG, E, N);
    norm0_k<<<((size_t)N * 256 + TB - 1) / TB, TB, 0, stream>>>(bufG, denom, b0, N);

    // ===== GAT layer 1 =====
    // h1 = x1 @ W1
    gemm64<<<dim3((256 / 64) * ((N + 63) / 64)), TB, 0, stream>>>(bufG, W1, bufH, N, 256, 256);
    alphas1_k<<<(N * 64 + TB - 1) / TB, TB, 0, stream>>>(bufH, a_src1, a_dst1, asrc, adst, N);
    hipMemsetAsync(emaxu, 0, (size_t)N * sizeof(unsigned), stream);
    hipMemsetAsync(denom, 0, (size_t)N * sizeof(float), stream);
    hipMemsetAsync(bufG, 0, szH * sizeof(float), stream);
    edge_scores1<<<(ET + TB - 1) / TB, TB, 0, stream>>>(ei, asrc, adst, escore, emaxu, E, N);
    edge_agg1<<<ET, TB, 0, stream>>>(ei, bufH, escore, emaxu, denom, bufG, E, N);
    norm1_k<<<((size_t)N * 256 + TB - 1) / TB, TB, 0, stream>>>(bufG, denom, b1, N);

    // ===== fused MLP head + softmax =====
    fused_mlp<<<(N + 15) / 16, TB, 0, stream>>>(bufG, lw1, lb1, lw2, lb2, lw3, lb3, out, N);
}

// Round 2
// 1420.974 us; speedup vs baseline: 1.8653x; 1.8653x over previous
//
#include <hip/hip_runtime.h>
#include <cstdint>
#include <cstddef>

#define F_IN   128
#define SLOPE  0.2f

typedef unsigned short u16;
typedef __attribute__((ext_vector_type(8))) short     bf16x8;
typedef __attribute__((ext_vector_type(8))) unsigned short u16x8;
typedef __attribute__((ext_vector_type(4))) float     f32x4;

// ---------- float -> bf16 (round-to-nearest-even) ----------
__device__ __forceinline__ u16 f2bf(float f) {
    unsigned u = __float_as_uint(f);
    unsigned r = u + 0x7FFFu + ((u >> 16) & 1u);
    return (u16)(r >> 16);
}

// ---------- float <-> order-preserving uint (for atomicMax on floats) ----------
__device__ __forceinline__ unsigned f2ord(float v) {
    unsigned b = __float_as_uint(v);
    return (b & 0x80000000u) ? ~b : (b | 0x80000000u);
}
__device__ __forceinline__ float ord2f(unsigned u) {
    return __uint_as_float((u & 0x80000000u) ? (u & 0x7FFFFFFFu) : ~u);
}

// ---------------- tiled fp32 GEMM: C[M,Nc] = A[M,K] @ B[K,Nc] ----------------
__global__ __launch_bounds__(256) void gemm64(
    const float* __restrict__ A, const float* __restrict__ B, float* __restrict__ C,
    int M, int Nc, int K) {
    __shared__ __align__(16) float As[16][65];
    __shared__ __align__(16) float Bs[16][65];
    int t  = threadIdx.x;
    int nb = Nc >> 6;
    int bx = blockIdx.x % nb;
    int by = blockIdx.x / nb;
    int tx = t & 15, ty = t >> 4;
    int row0 = by * 64, col0 = bx * 64;
    float acc[4][4] = {};
    for (int k0 = 0; k0 < K; k0 += 16) {
        int r  = t >> 2, kq = (t & 3) * 4;
        int gr = row0 + r;
        float4 av = make_float4(0.f, 0.f, 0.f, 0.f);
        if (gr < M) av = *(const float4*)(A + (size_t)gr * K + k0 + kq);
        As[kq + 0][r] = av.x; As[kq + 1][r] = av.y;
        As[kq + 2][r] = av.z; As[kq + 3][r] = av.w;
        int br = t >> 4, bc = (t & 15) * 4;
        float4 bv = *(const float4*)(B + (size_t)(k0 + br) * Nc + col0 + bc);
        Bs[br][bc + 0] = bv.x; Bs[br][bc + 1] = bv.y;
        Bs[br][bc + 2] = bv.z; Bs[br][bc + 3] = bv.w;
        __syncthreads();
        #pragma unroll
        for (int kk = 0; kk < 16; ++kk) {
            float a0 = As[kk][ty * 4 + 0], a1 = As[kk][ty * 4 + 1];
            float a2 = As[kk][ty * 4 + 2], a3 = As[kk][ty * 4 + 3];
            float b0 = Bs[kk][tx * 4 + 0], b1 = Bs[kk][tx * 4 + 1];
            float b2 = Bs[kk][tx * 4 + 2], b3 = Bs[kk][tx * 4 + 3];
            acc[0][0] += a0 * b0; acc[0][1] += a0 * b1; acc[0][2] += a0 * b2; acc[0][3] += a0 * b3;
            acc[1][0] += a1 * b0; acc[1][1] += a1 * b1; acc[1][2] += a1 * b2; acc[1][3] += a1 * b3;
            acc[2][0] += a2 * b0; acc[2][1] += a2 * b1; acc[2][2] += a2 * b2; acc[2][3] += a2 * b3;
            acc[3][0] += a3 * b0; acc[3][1] += a3 * b1; acc[3][2] += a3 * b2; acc[3][3] += a3 * b3;
        }
        __syncthreads();
    }
    #pragma unroll
    for (int i = 0; i < 4; ++i) {
        int gr = row0 + ty * 4 + i;
        if (gr < M) {
            #pragma unroll
            for (int j = 0; j < 4; ++j)
                C[(size_t)gr * Nc + col0 + tx * 4 + j] = acc[i][j];
        }
    }
}

// ---------------- alpha dot products ----------------
__global__ void alphas0_k(const float* __restrict__ h0, const float* __restrict__ a_src,
                          const float* __restrict__ a_dst, float* __restrict__ asrc,
                          float* __restrict__ adst, int N) {
    int gid = blockIdx.x * blockDim.x + threadIdx.x;
    int n = gid >> 6, lane = gid & 63;
    if (n >= N) return;
    #pragma unroll
    for (int h = 0; h < 4; ++h) {
        float v  = h0[(size_t)n * 256 + h * 64 + lane];
        float s1 = v * a_src[h * 64 + lane];
        float s2 = v * a_dst[h * 64 + lane];
        #pragma unroll
        for (int off = 32; off; off >>= 1) {
            s1 += __shfl_down(s1, off);
            s2 += __shfl_down(s2, off);
        }
        if (lane == 0) { asrc[n * 4 + h] = s1; adst[n * 4 + h] = s2; }
    }
}

__global__ void alphas1_k(const float* __restrict__ h1, const float* __restrict__ a_src,
                          const float* __restrict__ a_dst, float* __restrict__ asrc,
                          float* __restrict__ adst, int N) {
    int gid = blockIdx.x * blockDim.x + threadIdx.x;
    int n = gid >> 6, lane = gid & 63;
    if (n >= N) return;
    float s1 = 0.f, s2 = 0.f;
    #pragma unroll
    for (int k = 0; k < 4; ++k) {
        float v = h1[(size_t)n * 256 + k * 64 + lane];
        s1 += v * a_src[k * 64 + lane];
        s2 += v * a_dst[k * 64 + lane];
    }
    #pragma unroll
    for (int off = 32; off; off >>= 1) {
        s1 += __shfl_down(s1, off);
        s2 += __shfl_down(s2, off);
    }
    if (lane == 0) { asrc[n] = s1; adst[n] = s2; }
}

// ---------------- edge pass A: scores + segment max ----------------
__global__ void edge_scores0(const int* __restrict__ ei, const float* __restrict__ asrc,
                             const float* __restrict__ adst, float* __restrict__ escore,
                             unsigned* __restrict__ emaxu, int E, int N) {
    int e = blockIdx.x * blockDim.x + threadIdx.x;
    if (e >= E + N) return;
    int s, d; bool valid;
    if (e < E) { s = ei[e]; d = ei[E + e]; valid = (s != d); }
    else       { s = d = e - E; valid = true; }
    #pragma unroll
    for (int h = 0; h < 4; ++h) {
        float v = asrc[s * 4 + h] + adst[d * 4 + h];
        v = v >= 0.f ? v : SLOPE * v;
        if (!valid) v = -1e9f;
        escore[(size_t)e * 4 + h] = v;
        atomicMax(&emaxu[d * 4 + h], f2ord(v));
    }
}

__global__ void edge_scores1(const int* __restrict__ ei, const float* __restrict__ asrc,
                             const float* __restrict__ adst, float* __restrict__ escore,
                             unsigned* __restrict__ emaxu, int E, int N) {
    int e = blockIdx.x * blockDim.x + threadIdx.x;
    if (e >= E + N) return;
    int s, d; bool valid;
    if (e < E) { s = ei[e]; d = ei[E + e]; valid = (s != d); }
    else       { s = d = e - E; valid = true; }
    float v = asrc[s] + adst[d];
    v = v >= 0.f ? v : SLOPE * v;
    if (!valid) v = -1e9f;
    escore[e] = v;
    atomicMax(&emaxu[d], f2ord(v));
}

// ---------------- edge pass B ----------------
__global__ void edge_agg0(const int* __restrict__ ei, const float* __restrict__ h0,
                          const float* __restrict__ escore, const unsigned* __restrict__ emaxu,
                          float* __restrict__ denom, float* __restrict__ agg, int E, int N) {
    int gid = blockIdx.x * blockDim.x + threadIdx.x;
    int e = gid >> 6, lane = gid & 63;
    if (e >= E + N) return;
    int s, d;
    if (e < E) { s = ei[e]; d = ei[E + e]; }
    else       { s = d = e - E; }
    #pragma unroll
    for (int h = 0; h < 4; ++h) {
        float w = __expf(escore[(size_t)e * 4 + h] - ord2f(emaxu[d * 4 + h]));
        if (lane == 0) atomicAdd(&denom[d * 4 + h], w);
        if (w != 0.f)
            atomicAdd(&agg[(size_t)d * 256 + h * 64 + lane],
                      w * h0[(size_t)s * 256 + h * 64 + lane]);
    }
}

__global__ __launch_bounds__(256) void edge_agg1(
    const int* __restrict__ ei, const float* __restrict__ h1,
    const float* __restrict__ escore, const unsigned* __restrict__ emaxu,
    float* __restrict__ denom, float* __restrict__ agg, int E, int N) {
    int e = blockIdx.x, c = threadIdx.x;
    int s, d;
    if (e < E) { s = ei[e]; d = ei[E + e]; }
    else       { s = d = e - E; }
    float w = __expf(escore[e] - ord2f(emaxu[d]));
    if (w != 0.f)
        atomicAdd(&agg[(size_t)d * 256 + c], w * h1[(size_t)s * 256 + c]);
    if (c == 0) atomicAdd(&denom[d], w);
}

// ---------------- normalize + bias + relu ----------------
__global__ void norm0_k(float* __restrict__ agg, const float* __restrict__ denom,
                        const float* __restrict__ b, int N) {
    int i = blockIdx.x * blockDim.x + threadIdx.x;
    if (i >= N * 256) return;
    int n = i >> 8, c = i & 255, h = c >> 6;
    float v = agg[i] / denom[n * 4 + h] + b[c];
    agg[i] = v > 0.f ? v : 0.f;
}

__global__ void norm1_k(float* __restrict__ agg, const float* __restrict__ denom,
                        const float* __restrict__ b, int N) {
    int i = blockIdx.x * blockDim.x + threadIdx.x;
    if (i >= N * 256) return;
    int n = i >> 8, c = i & 255;
    float v = agg[i] / denom[n] + b[c];
    agg[i] = v > 0.f ? v : 0.f;
}

// ---------------- weight packing: fp32 [K,Nsrc] -> bf16 MFMA B-fragments ----------------
// out[((kt*NT + nt)*64 + lane)*8 + i] = bf16(W[kt*32 + (lane>>4)*8 + i][nt*16 + (lane&15)])
__global__ void pack_w(const float* __restrict__ W, u16* __restrict__ out,
                       int K, int Nsrc, int NT) {
    int gid  = blockIdx.x * blockDim.x + threadIdx.x;
    int lane = gid & 63, frag = gid >> 6;
    int KT = K >> 5;
    if (frag >= KT * NT) return;
    int nt = frag % NT, kt = frag / NT;
    int n  = nt * 16 + (lane & 15);
    int k0 = kt * 32 + ((lane >> 4) << 3);
    u16x8 v8;
    #pragma unroll
    for (int i = 0; i < 8; ++i) {
        float v = (n < Nsrc) ? W[(size_t)(k0 + i) * Nsrc + n] : 0.f;
        v8[i] = f2bf(v);
    }
    *(u16x8*)(out + (size_t)(frag * 64 + lane) * 8) = v8;
}

// ---------------- fused MLP via bf16 MFMA: 256 -> 512 -> 1024 -> 10 -> softmax ----------------
// 32 nodes/block, 512 threads (8 waves). Activations in LDS (bf16, row-XOR swizzled).
#define NB 32

__device__ __forceinline__ bf16x8 lds_afrag(const u16* buf, int Kdim, int row0, int kt, int lane) {
    int row = row0 + (lane & 15);
    int k   = kt * 32 + ((lane >> 4) << 3);
    int idx = (row * Kdim + k) ^ ((row & 7) << 3);
    return *(const bf16x8*)(buf + idx);
}

__global__ __launch_bounds__(512) void mlp_mfma(
    const float* __restrict__ m0,
    const u16* __restrict__ w1p, const float* __restrict__ lb1,
    const u16* __restrict__ w2p, const float* __restrict__ lb2,
    const u16* __restrict__ w3p, const float* __restrict__ lb3,
    float* __restrict__ out, int N) {
    __shared__ __align__(16) u16 ldsA0[32 * 256];
    __shared__ __align__(16) u16 ldsA1[32 * 512];
    __shared__ __align__(16) u16 ldsA2[32 * 1024];
    __shared__ float slog[32 * 16];

    int t = threadIdx.x, lane = t & 63, w = t >> 6;
    int nb = blockIdx.x * NB;

    slog[t] = 0.f;

    // stage input tile -> bf16 LDS (swizzled)
    #pragma unroll
    for (int u = 0; u < 2; ++u) {
        int unit = t + u * 512;                 // 1024 units: 32 rows x 32 k-octets
        int row = unit >> 5, kb = (unit & 31) << 3;
        int gn = nb + row;
        u16x8 v8;
        if (gn < N) {
            const float* p = m0 + (size_t)gn * 256 + kb;
            #pragma unroll
            for (int i = 0; i < 8; ++i) v8[i] = f2bf(p[i]);
        } else {
            v8 = (u16x8)0;
        }
        int idx = (row * 256 + kb) ^ ((row & 7) << 3);
        *(u16x8*)(ldsA0 + idx) = v8;
    }
    __syncthreads();

    // ---- layer 1: [32,256] @ [256,512]; wave w owns cols [64w, 64w+64) ----
    {
        f32x4 acc[2][4] = {};
        for (int kt = 0; kt < 8; ++kt) {
            bf16x8 a0 = lds_afrag(ldsA0, 256, 0,  kt, lane);
            bf16x8 a1 = lds_afrag(ldsA0, 256, 16, kt, lane);
            #pragma unroll
            for (int nt = 0; nt < 4; ++nt) {
                int ntg = w * 4 + nt;
                bf16x8 b = *(const bf16x8*)(w1p + ((size_t)(kt * 32 + ntg) * 64 + lane) * 8);
                acc[0][nt] = __builtin_amdgcn_mfma_f32_16x16x32_bf16(a0, b, acc[0][nt], 0, 0, 0);
                acc[1][nt] = __builtin_amdgcn_mfma_f32_16x16x32_bf16(a1, b, acc[1][nt], 0, 0, 0);
            }
        }
        #pragma unroll
        for (int mt = 0; mt < 2; ++mt)
            #pragma unroll
            for (int nt = 0; nt < 4; ++nt) {
                int col = w * 64 + nt * 16 + (lane & 15);
                float bv = lb1[col];
                #pragma unroll
                for (int j = 0; j < 4; ++j) {
                    int row = mt * 16 + ((lane >> 4) << 2) + j;
                    float v = acc[mt][nt][j] + bv;
                    v = v > 0.f ? v : 0.f;
                    ldsA1[(row * 512 + col) ^ ((row & 7) << 3)] = f2bf(v);
                }
            }
    }
    __syncthreads();

    // ---- layer 2: [32,512] @ [512,1024]; wave w owns cols [128w, 128w+128) ----
    {
        f32x4 acc[2][8] = {};
        for (int kt = 0; kt < 16; ++kt) {
            bf16x8 a0 = lds_afrag(ldsA1, 512, 0,  kt, lane);
            bf16x8 a1 = lds_afrag(ldsA1, 512, 16, kt, lane);
            #pragma unroll
            for (int nt = 0; nt < 8; ++nt) {
                int ntg = w * 8 + nt;
                bf16x8 b = *(const bf16x8*)(w2p + ((size_t)(kt * 64 + ntg) * 64 + lane) * 8);
                acc[0][nt] = __builtin_amdgcn_mfma_f32_16x16x32_bf16(a0, b, acc[0][nt], 0, 0, 0);
                acc[1][nt] = __builtin_amdgcn_mfma_f32_16x16x32_bf16(a1, b, acc[1][nt], 0, 0, 0);
            }
        }
        #pragma unroll
        for (int mt = 0; mt < 2; ++mt)
            #pragma unroll
            for (int nt = 0; nt < 8; ++nt) {
                int col = w * 128 + nt * 16 + (lane & 15);
                float bv = lb2[col];
                #pragma unroll
                for (int j = 0; j < 4; ++j) {
                    int row = mt * 16 + ((lane >> 4) << 2) + j;
                    float v = acc[mt][nt][j] + bv;
                    v = v > 0.f ? v : 0.f;
                    ldsA2[(row * 1024 + col) ^ ((row & 7) << 3)] = f2bf(v);
                }
            }
    }
    __syncthreads();

    // ---- layer 3: [32,1024] @ [1024,16(10 valid)]; wave w owns kt = 4w..4w+3 ----
    {
        f32x4 acc[2] = {};
        #pragma unroll
        for (int kk = 0; kk < 4; ++kk) {
            int kt = w * 4 + kk;
            bf16x8 a0 = lds_afrag(ldsA2, 1024, 0,  kt, lane);
            bf16x8 a1 = lds_afrag(ldsA2, 1024, 16, kt, lane);
            bf16x8 b  = *(const bf16x8*)(w3p + ((size_t)kt * 64 + lane) * 8);
            acc[0] = __builtin_amdgcn_mfma_f32_16x16x32_bf16(a0, b, acc[0], 0, 0, 0);
            acc[1] = __builtin_amdgcn_mfma_f32_16x16x32_bf16(a1, b, acc[1], 0, 0, 0);
        }
        int col = lane & 15;
        #pragma unroll
        for (int mt = 0; mt < 2; ++mt)
            #pragma unroll
            for (int j = 0; j < 4; ++j) {
                int row = mt * 16 + ((lane >> 4) << 2) + j;
                atomicAdd(&slog[row * 16 + col], acc[mt][j]);
            }
    }
    __syncthreads();

    // ---- bias + relu + softmax ----
    if (t < 32) {
        int gn = nb + t;
        if (gn < N) {
            float lg[10], m = -1e30f;
            #pragma unroll
            for (int k = 0; k < 10; ++k) {
                float v = slog[t * 16 + k] + lb3[k];
                v = v > 0.f ? v : 0.f;
                lg[k] = v;
                if (v > m) m = v;
            }
            float ssum = 0.f;
            #pragma unroll
            for (int k = 0; k < 10; ++k) { lg[k] = __expf(lg[k] - m); ssum += lg[k]; }
            float inv = 1.f / ssum;
            #pragma unroll
            for (int k = 0; k < 10; ++k) out[(size_t)gn * 10 + k] = lg[k] * inv;
        }
    }
}

// ---------------------------------------------------------------------------
extern "C" void kernel_launch(void* const* d_in, const int* in_sizes, int n_in,
                              void* d_out, int out_size, void* d_ws, size_t ws_size,
                              hipStream_t stream) {
    const float* x       = (const float*)d_in[0];
    const int*   ei      = (const int*)  d_in[1];
    const float* W0      = (const float*)d_in[2];
    const float* a_src0  = (const float*)d_in[3];
    const float* a_dst0  = (const float*)d_in[4];
    const float* b0      = (const float*)d_in[5];
    const float* W1      = (const float*)d_in[6];
    const float* a_src1  = (const float*)d_in[7];
    const float* a_dst1  = (const float*)d_in[8];
    const float* b1      = (const float*)d_in[9];
    const float* lw1     = (const float*)d_in[10];
    const float* lb1     = (const float*)d_in[11];
    const float* lw2     = (const float*)d_in[12];
    const float* lb2     = (const float*)d_in[13];
    const float* lw3     = (const float*)d_in[14];
    const float* lb3     = (const float*)d_in[15];
    float*       out     = (float*)d_out;

    const int N  = in_sizes[0] / F_IN;   // 50000
    const int E  = in_sizes[1] / 2;      // 400000
    const int ET = E + N;

    // workspace layout (floats)
    float* ws     = (float*)d_ws;
    size_t szH    = (size_t)N * 256;
    float* bufH   = ws;                       // h0, then h1
    float* bufG   = ws + szH;                 // agg0->x1, then agg1->m0
    float* asrc   = ws + 2 * szH;             // N*4
    float* adst   = asrc + (size_t)N * 4;
    unsigned* emaxu = (unsigned*)(adst + (size_t)N * 4);
    float* denom  = (float*)emaxu + (size_t)N * 4;
    float* escore = denom + (size_t)N * 4;    // ET*4
    u16*   w1p    = (u16*)(escore + (size_t)ET * 4);   // 256*512 bf16
    u16*   w2p    = w1p + 256 * 512;                    // 512*1024 bf16
    u16*   w3p    = w2p + 512 * 1024;                   // 1024*16 bf16

    const int TB = 256;

    // ===== pack MLP weights to bf16 fragments (overlaps with GAT work) =====
    pack_w<<<(8  * 32 * 64 + TB - 1) / TB, TB, 0, stream>>>(lw1, w1p, 256,  512,  32);
    pack_w<<<(16 * 64 * 64 + TB - 1) / TB, TB, 0, stream>>>(lw2, w2p, 512,  1024, 64);
    pack_w<<<(32 * 1  * 64 + TB - 1) / TB, TB, 0, stream>>>(lw3, w3p, 1024, 10,   1);

    // ===== GAT layer 0 =====
    gemm64<<<dim3((256 / 64) * ((N + 63) / 64)), TB, 0, stream>>>(x, W0, bufH, N, 256, F_IN);
    alphas0_k<<<(N * 64 + TB - 1) / TB, TB, 0, stream>>>(bufH, a_src0, a_dst0, asrc, adst, N);
    hipMemsetAsync(emaxu, 0, (size_t)N * 4 * sizeof(unsigned), stream);
    hipMemsetAsync(denom, 0, (size_t)N * 4 * sizeof(float), stream);
    hipMemsetAsync(bufG, 0, szH * sizeof(float), stream);
    edge_scores0<<<(ET + TB - 1) / TB, TB, 0, stream>>>(ei, asrc, adst, escore, emaxu, E, N);
    edge_agg0<<<((size_t)ET * 64 + TB - 1) / TB, TB, 0, stream>>>(ei, bufH, escore, emaxu, denom, bufG, E, N);
    norm0_k<<<((size_t)N * 256 + TB - 1) / TB, TB, 0, stream>>>(bufG, denom, b0, N);

    // ===== GAT layer 1 =====
    gemm64<<<dim3((256 / 64) * ((N + 63) / 64)), TB, 0, stream>>>(bufG, W1, bufH, N, 256, 256);
    alphas1_k<<<(N * 64 + TB - 1) / TB, TB, 0, stream>>>(bufH, a_src1, a_dst1, asrc, adst, N);
    hipMemsetAsync(emaxu, 0, (size_t)N * sizeof(unsigned), stream);
    hipMemsetAsync(denom, 0, (size_t)N * sizeof(float), stream);
    hipMemsetAsync(bufG, 0, szH * sizeof(float), stream);
    edge_scores1<<<(ET + TB - 1) / TB, TB, 0, stream>>>(ei, asrc, adst, escore, emaxu, E, N);
    edge_agg1<<<ET, TB, 0, stream>>>(ei, bufH, escore, emaxu, denom, bufG, E, N);
    norm1_k<<<((size_t)N * 256 + TB - 1) / TB, TB, 0, stream>>>(bufG, denom, b1, N);

    // ===== fused MLP head (bf16 MFMA) + softmax =====
    mlp_mfma<<<(N + NB - 1) / NB, 512, 0, stream>>>(bufG, w1p, lb1, w2p, lb2, w3p, lb3, out, N);
}

// Round 3
// 602.871 us; speedup vs baseline: 4.3965x; 2.3570x over previous
//
#include <hip/hip_runtime.h>
#include <cstdint>
#include <cstddef>

#define F_IN   128
#define SLOPE  0.2f

typedef unsigned short u16;
typedef __attribute__((ext_vector_type(8))) short     bf16x8;
typedef __attribute__((ext_vector_type(8))) unsigned short u16x8;
typedef __attribute__((ext_vector_type(4))) float     f32x4;

// ---------- float -> bf16 (round-to-nearest-even) ----------
__device__ __forceinline__ u16 f2bf(float f) {
    unsigned u = __float_as_uint(f);
    unsigned r = u + 0x7FFFu + ((u >> 16) & 1u);
    return (u16)(r >> 16);
}

__device__ __forceinline__ float lrelu(float v) { return v >= 0.f ? v : SLOPE * v; }

// ---------------- tiled fp32 GEMM: C[M,Nc] = A[M,K] @ B[K,Nc] ----------------
__global__ __launch_bounds__(256) void gemm64(
    const float* __restrict__ A, const float* __restrict__ B, float* __restrict__ C,
    int M, int Nc, int K) {
    __shared__ __align__(16) float As[16][65];
    __shared__ __align__(16) float Bs[16][65];
    int t  = threadIdx.x;
    int nb = Nc >> 6;
    int bx = blockIdx.x % nb;
    int by = blockIdx.x / nb;
    int tx = t & 15, ty = t >> 4;
    int row0 = by * 64, col0 = bx * 64;
    float acc[4][4] = {};
    for (int k0 = 0; k0 < K; k0 += 16) {
        int r  = t >> 2, kq = (t & 3) * 4;
        int gr = row0 + r;
        float4 av = make_float4(0.f, 0.f, 0.f, 0.f);
        if (gr < M) av = *(const float4*)(A + (size_t)gr * K + k0 + kq);
        As[kq + 0][r] = av.x; As[kq + 1][r] = av.y;
        As[kq + 2][r] = av.z; As[kq + 3][r] = av.w;
        int br = t >> 4, bc = (t & 15) * 4;
        float4 bv = *(const float4*)(B + (size_t)(k0 + br) * Nc + col0 + bc);
        Bs[br][bc + 0] = bv.x; Bs[br][bc + 1] = bv.y;
        Bs[br][bc + 2] = bv.z; Bs[br][bc + 3] = bv.w;
        __syncthreads();
        #pragma unroll
        for (int kk = 0; kk < 16; ++kk) {
            float a0 = As[kk][ty * 4 + 0], a1 = As[kk][ty * 4 + 1];
            float a2 = As[kk][ty * 4 + 2], a3 = As[kk][ty * 4 + 3];
            float b0 = Bs[kk][tx * 4 + 0], b1 = Bs[kk][tx * 4 + 1];
            float b2 = Bs[kk][tx * 4 + 2], b3 = Bs[kk][tx * 4 + 3];
            acc[0][0] += a0 * b0; acc[0][1] += a0 * b1; acc[0][2] += a0 * b2; acc[0][3] += a0 * b3;
            acc[1][0] += a1 * b0; acc[1][1] += a1 * b1; acc[1][2] += a1 * b2; acc[1][3] += a1 * b3;
            acc[2][0] += a2 * b0; acc[2][1] += a2 * b1; acc[2][2] += a2 * b2; acc[2][3] += a2 * b3;
            acc[3][0] += a3 * b0; acc[3][1] += a3 * b1; acc[3][2] += a3 * b2; acc[3][3] += a3 * b3;
        }
        __syncthreads();
    }
    #pragma unroll
    for (int i = 0; i < 4; ++i) {
        int gr = row0 + ty * 4 + i;
        if (gr < M) {
            #pragma unroll
            for (int j = 0; j < 4; ++j)
                C[(size_t)gr * Nc + col0 + tx * 4 + j] = acc[i][j];
        }
    }
}

// ---------------- alpha dot products ----------------
__global__ void alphas0_k(const float* __restrict__ h0, const float* __restrict__ a_src,
                          const float* __restrict__ a_dst, float* __restrict__ asrc,
                          float* __restrict__ adst, int N) {
    int gid = blockIdx.x * blockDim.x + threadIdx.x;
    int n = gid >> 6, lane = gid & 63;
    if (n >= N) return;
    #pragma unroll
    for (int h = 0; h < 4; ++h) {
        float v  = h0[(size_t)n * 256 + h * 64 + lane];
        float s1 = v * a_src[h * 64 + lane];
        float s2 = v * a_dst[h * 64 + lane];
        #pragma unroll
        for (int off = 32; off; off >>= 1) {
            s1 += __shfl_down(s1, off);
            s2 += __shfl_down(s2, off);
        }
        if (lane == 0) { asrc[n * 4 + h] = s1; adst[n * 4 + h] = s2; }
    }
}

__global__ void alphas1_k(const float* __restrict__ h1, const float* __restrict__ a_src,
                          const float* __restrict__ a_dst, float* __restrict__ asrc,
                          float* __restrict__ adst, int N) {
    int gid = blockIdx.x * blockDim.x + threadIdx.x;
    int n = gid >> 6, lane = gid & 63;
    if (n >= N) return;
    float s1 = 0.f, s2 = 0.f;
    #pragma unroll
    for (int k = 0; k < 4; ++k) {
        float v = h1[(size_t)n * 256 + k * 64 + lane];
        s1 += v * a_src[k * 64 + lane];
        s2 += v * a_dst[k * 64 + lane];
    }
    #pragma unroll
    for (int off = 32; off; off >>= 1) {
        s1 += __shfl_down(s1, off);
        s2 += __shfl_down(s2, off);
    }
    if (lane == 0) { asrc[n] = s1; adst[n] = s2; }
}

// ---------------- CSR build (by destination; valid edges + self-loops) ----------------
__global__ void deg_init(int* __restrict__ deg, int N) {
    int i = blockIdx.x * blockDim.x + threadIdx.x;
    if (i < N) deg[i] = 1;                      // self-loop
}

__global__ void count_deg(const int* __restrict__ ei, int* __restrict__ deg, int E) {
    int e = blockIdx.x * blockDim.x + threadIdx.x;
    if (e >= E) return;
    int s = ei[e], d = ei[E + e];
    if (s != d) atomicAdd(&deg[d], 1);
}

__global__ void scan1(const int* __restrict__ deg, int* __restrict__ part,
                      int* __restrict__ bsum, int N) {
    __shared__ int sm[256];
    int i = blockIdx.x * 256 + threadIdx.x;
    int v = (i < N) ? deg[i] : 0;
    sm[threadIdx.x] = v; __syncthreads();
    for (int off = 1; off < 256; off <<= 1) {
        int tv = (threadIdx.x >= off) ? sm[threadIdx.x - off] : 0;
        __syncthreads();
        sm[threadIdx.x] += tv;
        __syncthreads();
    }
    if (i < N) part[i] = sm[threadIdx.x] - v;   // exclusive within block
    if (threadIdx.x == 255) bsum[blockIdx.x] = sm[255];
}

__global__ void scan2(int* __restrict__ bsum, int nb) {
    __shared__ int sm[256];
    __shared__ int carry;
    if (threadIdx.x == 0) carry = 0;
    __syncthreads();
    for (int base = 0; base < nb; base += 256) {
        int i = base + threadIdx.x;
        int v = (i < nb) ? bsum[i] : 0;
        sm[threadIdx.x] = v; __syncthreads();
        for (int off = 1; off < 256; off <<= 1) {
            int tv = (threadIdx.x >= off) ? sm[threadIdx.x - off] : 0;
            __syncthreads();
            sm[threadIdx.x] += tv;
            __syncthreads();
        }
        if (i < nb) bsum[i] = sm[threadIdx.x] - v + carry;
        __syncthreads();
        if (threadIdx.x == 0) carry += sm[255];
        __syncthreads();
    }
}

__global__ void scan3(const int* __restrict__ deg, const int* __restrict__ part,
                      const int* __restrict__ bsum, int* __restrict__ rowp,
                      int* __restrict__ cursor, int N) {
    int i = blockIdx.x * blockDim.x + threadIdx.x;
    if (i >= N) return;
    int r = part[i] + bsum[i >> 8];
    rowp[i] = r;
    cursor[i] = r;
    if (i == N - 1) rowp[N] = r + deg[i];
}

__global__ void scatter_k(const int* __restrict__ ei, int* __restrict__ cursor,
                          int* __restrict__ csr, int E, int N) {
    int e = blockIdx.x * blockDim.x + threadIdx.x;
    if (e >= E + N) return;
    int s, d;
    if (e < E) { s = ei[e]; d = ei[E + e]; if (s == d) return; }
    else       { s = d = e - E; }
    int pos = atomicAdd(&cursor[d], 1);
    csr[pos] = s;
}

// ---------------- GAT gather-aggregate (fused max/softmax/agg/norm/bias/relu) ----------------
// layer0: one wave per node; 4 heads x 64 channels.
__global__ void gat_gather0(const int* __restrict__ csr, const int* __restrict__ rowp,
                            const float* __restrict__ h0, const float* __restrict__ asrc,
                            const float* __restrict__ adst, const float* __restrict__ b,
                            float* __restrict__ outx, int N) {
    int gid = blockIdx.x * blockDim.x + threadIdx.x;
    int n = gid >> 6, lane = gid & 63;
    if (n >= N) return;
    int beg = rowp[n], end = rowp[n + 1];
    float4 ad = *(const float4*)(adst + (size_t)n * 4);
    // pass 1: segment max (lane-parallel over edges)
    float m0 = -1e30f, m1 = -1e30f, m2 = -1e30f, m3 = -1e30f;
    for (int i = beg + lane; i < end; i += 64) {
        int s = csr[i];
        float4 as = *(const float4*)(asrc + (size_t)s * 4);
        m0 = fmaxf(m0, lrelu(as.x + ad.x));
        m1 = fmaxf(m1, lrelu(as.y + ad.y));
        m2 = fmaxf(m2, lrelu(as.z + ad.z));
        m3 = fmaxf(m3, lrelu(as.w + ad.w));
    }
    #pragma unroll
    for (int off = 32; off; off >>= 1) {
        m0 = fmaxf(m0, __shfl_xor(m0, off));
        m1 = fmaxf(m1, __shfl_xor(m1, off));
        m2 = fmaxf(m2, __shfl_xor(m2, off));
        m3 = fmaxf(m3, __shfl_xor(m3, off));
    }
    // pass 2: weighted gather
    float acc0 = 0.f, acc1 = 0.f, acc2 = 0.f, acc3 = 0.f;
    float den0 = 0.f, den1 = 0.f, den2 = 0.f, den3 = 0.f;
    for (int i = beg; i < end; ++i) {
        int s = csr[i];
        float4 as = *(const float4*)(asrc + (size_t)s * 4);
        float w0 = __expf(lrelu(as.x + ad.x) - m0);
        float w1 = __expf(lrelu(as.y + ad.y) - m1);
        float w2 = __expf(lrelu(as.z + ad.z) - m2);
        float w3 = __expf(lrelu(as.w + ad.w) - m3);
        den0 += w0; den1 += w1; den2 += w2; den3 += w3;
        const float* hs = h0 + (size_t)s * 256;
        acc0 += w0 * hs[lane];
        acc1 += w1 * hs[64 + lane];
        acc2 += w2 * hs[128 + lane];
        acc3 += w3 * hs[192 + lane];
    }
    float* po = outx + (size_t)n * 256;
    float v;
    v = acc0 / den0 + b[lane];       po[lane]       = v > 0.f ? v : 0.f;
    v = acc1 / den1 + b[64 + lane];  po[64 + lane]  = v > 0.f ? v : 0.f;
    v = acc2 / den2 + b[128 + lane]; po[128 + lane] = v > 0.f ? v : 0.f;
    v = acc3 / den3 + b[192 + lane]; po[192 + lane] = v > 0.f ? v : 0.f;
}

// layer1: one wave per node; 1 head x 256 channels.
__global__ void gat_gather1(const int* __restrict__ csr, const int* __restrict__ rowp,
                            const float* __restrict__ h1, const float* __restrict__ asrc,
                            const float* __restrict__ adst, const float* __restrict__ b,
                            float* __restrict__ outx, int N) {
    int gid = blockIdx.x * blockDim.x + threadIdx.x;
    int n = gid >> 6, lane = gid & 63;
    if (n >= N) return;
    int beg = rowp[n], end = rowp[n + 1];
    float adn = adst[n];
    float mx = -1e30f;
    for (int i = beg + lane; i < end; i += 64) {
        int s = csr[i];
        mx = fmaxf(mx, lrelu(asrc[s] + adn));
    }
    #pragma unroll
    for (int off = 32; off; off >>= 1) mx = fmaxf(mx, __shfl_xor(mx, off));
    float acc0 = 0.f, acc1 = 0.f, acc2 = 0.f, acc3 = 0.f, den = 0.f;
    for (int i = beg; i < end; ++i) {
        int s = csr[i];
        float w = __expf(lrelu(asrc[s] + adn) - mx);
        den += w;
        const float* hs = h1 + (size_t)s * 256;
        acc0 += w * hs[lane];
        acc1 += w * hs[64 + lane];
        acc2 += w * hs[128 + lane];
        acc3 += w * hs[192 + lane];
    }
    float inv = 1.f / den;
    float* po = outx + (size_t)n * 256;
    float v;
    v = acc0 * inv + b[lane];       po[lane]       = v > 0.f ? v : 0.f;
    v = acc1 * inv + b[64 + lane];  po[64 + lane]  = v > 0.f ? v : 0.f;
    v = acc2 * inv + b[128 + lane]; po[128 + lane] = v > 0.f ? v : 0.f;
    v = acc3 * inv + b[192 + lane]; po[192 + lane] = v > 0.f ? v : 0.f;
}

// ---------------- weight packing: fp32 [K,Nsrc] -> bf16 MFMA B-fragments ----------------
__global__ void pack_w(const float* __restrict__ W, u16* __restrict__ out,
                       int K, int Nsrc, int NT) {
    int gid  = blockIdx.x * blockDim.x + threadIdx.x;
    int lane = gid & 63, frag = gid >> 6;
    int KT = K >> 5;
    if (frag >= KT * NT) return;
    int nt = frag % NT, kt = frag / NT;
    int n  = nt * 16 + (lane & 15);
    int k0 = kt * 32 + ((lane >> 4) << 3);
    u16x8 v8;
    #pragma unroll
    for (int i = 0; i < 8; ++i) {
        float v = (n < Nsrc) ? W[(size_t)(k0 + i) * Nsrc + n] : 0.f;
        v8[i] = f2bf(v);
    }
    *(u16x8*)(out + (size_t)(frag * 64 + lane) * 8) = v8;
}

// ---------------- fused MLP via bf16 MFMA: 256 -> 512 -> 1024 -> 10 -> softmax ----------------
#define NB 32

__device__ __forceinline__ bf16x8 lds_afrag(const u16* buf, int Kdim, int row0, int kt, int lane) {
    int row = row0 + (lane & 15);
    int k   = kt * 32 + ((lane >> 4) << 3);
    int idx = (row * Kdim + k) ^ ((row & 7) << 3);
    return *(const bf16x8*)(buf + idx);
}

__global__ __launch_bounds__(512) void mlp_mfma(
    const float* __restrict__ m0,
    const u16* __restrict__ w1p, const float* __restrict__ lb1,
    const u16* __restrict__ w2p, const float* __restrict__ lb2,
    const u16* __restrict__ w3p, const float* __restrict__ lb3,
    float* __restrict__ out, int N) {
    __shared__ __align__(16) u16 ldsA0[32 * 256];
    __shared__ __align__(16) u16 ldsA1[32 * 512];
    __shared__ __align__(16) u16 ldsA2[32 * 1024];
    __shared__ float slog[32 * 16];

    int t = threadIdx.x, lane = t & 63, w = t >> 6;
    int nb = blockIdx.x * NB;

    slog[t] = 0.f;

    #pragma unroll
    for (int u = 0; u < 2; ++u) {
        int unit = t + u * 512;
        int row = unit >> 5, kb = (unit & 31) << 3;
        int gn = nb + row;
        u16x8 v8;
        if (gn < N) {
            const float* p = m0 + (size_t)gn * 256 + kb;
            #pragma unroll
            for (int i = 0; i < 8; ++i) v8[i] = f2bf(p[i]);
        } else {
            v8 = (u16x8)0;
        }
        int idx = (row * 256 + kb) ^ ((row & 7) << 3);
        *(u16x8*)(ldsA0 + idx) = v8;
    }
    __syncthreads();

    // ---- layer 1 ----
    {
        f32x4 acc[2][4] = {};
        for (int kt = 0; kt < 8; ++kt) {
            bf16x8 a0 = lds_afrag(ldsA0, 256, 0,  kt, lane);
            bf16x8 a1 = lds_afrag(ldsA0, 256, 16, kt, lane);
            #pragma unroll
            for (int nt = 0; nt < 4; ++nt) {
                int ntg = w * 4 + nt;
                bf16x8 b = *(const bf16x8*)(w1p + ((size_t)(kt * 32 + ntg) * 64 + lane) * 8);
                acc[0][nt] = __builtin_amdgcn_mfma_f32_16x16x32_bf16(a0, b, acc[0][nt], 0, 0, 0);
                acc[1][nt] = __builtin_amdgcn_mfma_f32_16x16x32_bf16(a1, b, acc[1][nt], 0, 0, 0);
            }
        }
        #pragma unroll
        for (int mt = 0; mt < 2; ++mt)
            #pragma unroll
            for (int nt = 0; nt < 4; ++nt) {
                int col = w * 64 + nt * 16 + (lane & 15);
                float bv = lb1[col];
                #pragma unroll
                for (int j = 0; j < 4; ++j) {
                    int row = mt * 16 + ((lane >> 4) << 2) + j;
                    float v = acc[mt][nt][j] + bv;
                    v = v > 0.f ? v : 0.f;
                    ldsA1[(row * 512 + col) ^ ((row & 7) << 3)] = f2bf(v);
                }
            }
    }
    __syncthreads();

    // ---- layer 2 ----
    {
        f32x4 acc[2][8] = {};
        for (int kt = 0; kt < 16; ++kt) {
            bf16x8 a0 = lds_afrag(ldsA1, 512, 0,  kt, lane);
            bf16x8 a1 = lds_afrag(ldsA1, 512, 16, kt, lane);
            #pragma unroll
            for (int nt = 0; nt < 8; ++nt) {
                int ntg = w * 8 + nt;
                bf16x8 b = *(const bf16x8*)(w2p + ((size_t)(kt * 64 + ntg) * 64 + lane) * 8);
                acc[0][nt] = __builtin_amdgcn_mfma_f32_16x16x32_bf16(a0, b, acc[0][nt], 0, 0, 0);
                acc[1][nt] = __builtin_amdgcn_mfma_f32_16x16x32_bf16(a1, b, acc[1][nt], 0, 0, 0);
            }
        }
        #pragma unroll
        for (int mt = 0; mt < 2; ++mt)
            #pragma unroll
            for (int nt = 0; nt < 8; ++nt) {
                int col = w * 128 + nt * 16 + (lane & 15);
                float bv = lb2[col];
                #pragma unroll
                for (int j = 0; j < 4; ++j) {
                    int row = mt * 16 + ((lane >> 4) << 2) + j;
                    float v = acc[mt][nt][j] + bv;
                    v = v > 0.f ? v : 0.f;
                    ldsA2[(row * 1024 + col) ^ ((row & 7) << 3)] = f2bf(v);
                }
            }
    }
    __syncthreads();

    // ---- layer 3 ----
    {
        f32x4 acc[2] = {};
        #pragma unroll
        for (int kk = 0; kk < 4; ++kk) {
            int kt = w * 4 + kk;
            bf16x8 a0 = lds_afrag(ldsA2, 1024, 0,  kt, lane);
            bf16x8 a1 = lds_afrag(ldsA2, 1024, 16, kt, lane);
            bf16x8 b  = *(const bf16x8*)(w3p + ((size_t)kt * 64 + lane) * 8);
            acc[0] = __builtin_amdgcn_mfma_f32_16x16x32_bf16(a0, b, acc[0], 0, 0, 0);
            acc[1] = __builtin_amdgcn_mfma_f32_16x16x32_bf16(a1, b, acc[1], 0, 0, 0);
        }
        int col = lane & 15;
        #pragma unroll
        for (int mt = 0; mt < 2; ++mt)
            #pragma unroll
            for (int j = 0; j < 4; ++j) {
                int row = mt * 16 + ((lane >> 4) << 2) + j;
                atomicAdd(&slog[row * 16 + col], acc[mt][j]);
            }
    }
    __syncthreads();

    if (t < 32) {
        int gn = nb + t;
        if (gn < N) {
            float lg[10], m = -1e30f;
            #pragma unroll
            for (int k = 0; k < 10; ++k) {
                float v = slog[t * 16 + k] + lb3[k];
                v = v > 0.f ? v : 0.f;
                lg[k] = v;
                if (v > m) m = v;
            }
            float ssum = 0.f;
            #pragma unroll
            for (int k = 0; k < 10; ++k) { lg[k] = __expf(lg[k] - m); ssum += lg[k]; }
            float inv = 1.f / ssum;
            #pragma unroll
            for (int k = 0; k < 10; ++k) out[(size_t)gn * 10 + k] = lg[k] * inv;
        }
    }
}

// ---------------------------------------------------------------------------
extern "C" void kernel_launch(void* const* d_in, const int* in_sizes, int n_in,
                              void* d_out, int out_size, void* d_ws, size_t ws_size,
                              hipStream_t stream) {
    const float* x       = (const float*)d_in[0];
    const int*   ei      = (const int*)  d_in[1];
    const float* W0      = (const float*)d_in[2];
    const float* a_src0  = (const float*)d_in[3];
    const float* a_dst0  = (const float*)d_in[4];
    const float* b0      = (const float*)d_in[5];
    const float* W1      = (const float*)d_in[6];
    const float* a_src1  = (const float*)d_in[7];
    const float* a_dst1  = (const float*)d_in[8];
    const float* b1      = (const float*)d_in[9];
    const float* lw1     = (const float*)d_in[10];
    const float* lb1     = (const float*)d_in[11];
    const float* lw2     = (const float*)d_in[12];
    const float* lb2     = (const float*)d_in[13];
    const float* lw3     = (const float*)d_in[14];
    const float* lb3     = (const float*)d_in[15];
    float*       out     = (float*)d_out;

    const int N  = in_sizes[0] / F_IN;   // 50000
    const int E  = in_sizes[1] / 2;      // 400000
    const int ET = E + N;

    // workspace layout
    float* ws   = (float*)d_ws;
    size_t szH  = (size_t)N * 256;
    float* bufH = ws;                         // h0 / h1
    float* bufG = ws + szH;                   // x1 / m0
    float* asrc = ws + 2 * szH;               // N*4 (layer0) or N (layer1)
    float* adst = asrc + (size_t)N * 4;       // N*4
    u16*   w1p  = (u16*)(adst + (size_t)N * 4);          // 256*512
    u16*   w2p  = w1p + 256 * 512;                       // 512*1024
    u16*   w3p  = w2p + 512 * 1024;                      // 1024*16
    int*   deg  = (int*)(w3p + 1024 * 16);
    int*   rowp   = deg + N;                  // N+1
    int*   cursor = rowp + N + 1;
    int*   part   = cursor + N;
    int*   bsum   = part + N;                 // 256
    int*   csr    = bsum + 256;               // ET

    const int TB  = 256;
    const int nb1 = (N + 255) / 256;

    // ===== pack MLP weights =====
    pack_w<<<(8  * 32 * 64 + TB - 1) / TB, TB, 0, stream>>>(lw1, w1p, 256,  512,  32);
    pack_w<<<(16 * 64 * 64 + TB - 1) / TB, TB, 0, stream>>>(lw2, w2p, 512,  1024, 64);
    pack_w<<<(32 * 1  * 64 + TB - 1) / TB, TB, 0, stream>>>(lw3, w3p, 1024, 10,   1);

    // ===== build CSR (dst-sorted; valid edges + self-loops) =====
    deg_init<<<nb1, TB, 0, stream>>>(deg, N);
    count_deg<<<(E + TB - 1) / TB, TB, 0, stream>>>(ei, deg, E);
    scan1<<<nb1, TB, 0, stream>>>(deg, part, bsum, N);
    scan2<<<1, TB, 0, stream>>>(bsum, nb1);
    scan3<<<nb1, TB, 0, stream>>>(deg, part, bsum, rowp, cursor, N);
    scatter_k<<<(ET + TB - 1) / TB, TB, 0, stream>>>(ei, cursor, csr, E, N);

    // ===== GAT layer 0 =====
    gemm64<<<dim3((256 / 64) * ((N + 63) / 64)), TB, 0, stream>>>(x, W0, bufH, N, 256, F_IN);
    alphas0_k<<<(N * 64 + TB - 1) / TB, TB, 0, stream>>>(bufH, a_src0, a_dst0, asrc, adst, N);
    gat_gather0<<<((size_t)N * 64 + TB - 1) / TB, TB, 0, stream>>>(csr, rowp, bufH, asrc, adst, b0, bufG, N);

    // ===== GAT layer 1 =====
    gemm64<<<dim3((256 / 64) * ((N + 63) / 64)), TB, 0, stream>>>(bufG, W1, bufH, N, 256, 256);
    alphas1_k<<<(N * 64 + TB - 1) / TB, TB, 0, stream>>>(bufH, a_src1, a_dst1, asrc, adst, N);
    gat_gather1<<<((size_t)N * 64 + TB - 1) / TB, TB, 0, stream>>>(csr, rowp, bufH, asrc, adst, b1, bufG, N);

    // ===== fused MLP head (bf16 MFMA) + softmax =====
    mlp_mfma<<<(N + NB - 1) / NB, 512, 0, stream>>>(bufG, w1p, lb1, w2p, lb2, w3p, lb3, out, N);
}

// Round 4
// 460.091 us; speedup vs baseline: 5.7608x; 1.3103x over previous
//
#include <hip/hip_runtime.h>
#include <cstdint>
#include <cstddef>

#define F_IN   128
#define SLOPE  0.2f

typedef unsigned short u16;
typedef __attribute__((ext_vector_type(8))) short     bf16x8;
typedef __attribute__((ext_vector_type(8))) unsigned short u16x8;
typedef __attribute__((ext_vector_type(4))) unsigned short u16x4;
typedef __attribute__((ext_vector_type(4))) float     f32x4;

// ---------- float -> bf16 (round-to-nearest-even) ----------
__device__ __forceinline__ u16 f2bf(float f) {
    unsigned u = __float_as_uint(f);
    unsigned r = u + 0x7FFFu + ((u >> 16) & 1u);
    return (u16)(r >> 16);
}
__device__ __forceinline__ float bf2f(u16 h) {
    return __uint_as_float(((unsigned)h) << 16);
}

__device__ __forceinline__ float lrelu(float v) { return v >= 0.f ? v : SLOPE * v; }

// ---------------- alpha dot products ----------------
__global__ void alphas0_k(const float* __restrict__ h0, const float* __restrict__ a_src,
                          const float* __restrict__ a_dst, float* __restrict__ asrc,
                          float* __restrict__ adst, int N) {
    int gid = blockIdx.x * blockDim.x + threadIdx.x;
    int n = gid >> 6, lane = gid & 63;
    if (n >= N) return;
    #pragma unroll
    for (int h = 0; h < 4; ++h) {
        float v  = h0[(size_t)n * 256 + h * 64 + lane];
        float s1 = v * a_src[h * 64 + lane];
        float s2 = v * a_dst[h * 64 + lane];
        #pragma unroll
        for (int off = 32; off; off >>= 1) {
            s1 += __shfl_down(s1, off);
            s2 += __shfl_down(s2, off);
        }
        if (lane == 0) { asrc[n * 4 + h] = s1; adst[n * 4 + h] = s2; }
    }
}

__global__ void alphas1_k(const float* __restrict__ h1, const float* __restrict__ a_src,
                          const float* __restrict__ a_dst, float* __restrict__ asrc,
                          float* __restrict__ adst, int N) {
    int gid = blockIdx.x * blockDim.x + threadIdx.x;
    int n = gid >> 6, lane = gid & 63;
    if (n >= N) return;
    float s1 = 0.f, s2 = 0.f;
    #pragma unroll
    for (int k = 0; k < 4; ++k) {
        float v = h1[(size_t)n * 256 + k * 64 + lane];
        s1 += v * a_src[k * 64 + lane];
        s2 += v * a_dst[k * 64 + lane];
    }
    #pragma unroll
    for (int off = 32; off; off >>= 1) {
        s1 += __shfl_down(s1, off);
        s2 += __shfl_down(s2, off);
    }
    if (lane == 0) { asrc[n] = s1; adst[n] = s2; }
}

// ---------------- CSR build (by destination; valid edges + self-loops) ----------------
__global__ void deg_init(int* __restrict__ deg, int N) {
    int i = blockIdx.x * blockDim.x + threadIdx.x;
    if (i < N) deg[i] = 1;                      // self-loop
}

__global__ void count_deg(const int* __restrict__ ei, int* __restrict__ deg, int E) {
    int e = blockIdx.x * blockDim.x + threadIdx.x;
    if (e >= E) return;
    int s = ei[e], d = ei[E + e];
    if (s != d) atomicAdd(&deg[d], 1);
}

__global__ void scan1(const int* __restrict__ deg, int* __restrict__ part,
                      int* __restrict__ bsum, int N) {
    __shared__ int sm[256];
    int i = blockIdx.x * 256 + threadIdx.x;
    int v = (i < N) ? deg[i] : 0;
    sm[threadIdx.x] = v; __syncthreads();
    for (int off = 1; off < 256; off <<= 1) {
        int tv = (threadIdx.x >= off) ? sm[threadIdx.x - off] : 0;
        __syncthreads();
        sm[threadIdx.x] += tv;
        __syncthreads();
    }
    if (i < N) part[i] = sm[threadIdx.x] - v;   // exclusive within block
    if (threadIdx.x == 255) bsum[blockIdx.x] = sm[255];
}

__global__ void scan2(int* __restrict__ bsum, int nb) {
    __shared__ int sm[256];
    __shared__ int carry;
    if (threadIdx.x == 0) carry = 0;
    __syncthreads();
    for (int base = 0; base < nb; base += 256) {
        int i = base + threadIdx.x;
        int v = (i < nb) ? bsum[i] : 0;
        sm[threadIdx.x] = v; __syncthreads();
        for (int off = 1; off < 256; off <<= 1) {
            int tv = (threadIdx.x >= off) ? sm[threadIdx.x - off] : 0;
            __syncthreads();
            sm[threadIdx.x] += tv;
            __syncthreads();
        }
        if (i < nb) bsum[i] = sm[threadIdx.x] - v + carry;
        __syncthreads();
        if (threadIdx.x == 0) carry += sm[255];
        __syncthreads();
    }
}

__global__ void scan3(const int* __restrict__ deg, const int* __restrict__ part,
                      const int* __restrict__ bsum, int* __restrict__ rowp,
                      int* __restrict__ cursor, int N) {
    int i = blockIdx.x * blockDim.x + threadIdx.x;
    if (i >= N) return;
    int r = part[i] + bsum[i >> 8];
    rowp[i] = r;
    cursor[i] = r;
    if (i == N - 1) rowp[N] = r + deg[i];
}

__global__ void scatter_k(const int* __restrict__ ei, int* __restrict__ cursor,
                          int* __restrict__ csr, int E, int N) {
    int e = blockIdx.x * blockDim.x + threadIdx.x;
    if (e >= E + N) return;
    int s, d;
    if (e < E) { s = ei[e]; d = ei[E + e]; if (s == d) return; }
    else       { s = d = e - E; }
    int pos = atomicAdd(&cursor[d], 1);
    csr[pos] = s;
}

// ---------------- GAT gather-aggregate (fused max/softmax/agg/norm/bias/relu) ----------------
__global__ void gat_gather0(const int* __restrict__ csr, const int* __restrict__ rowp,
                            const float* __restrict__ h0, const float* __restrict__ asrc,
                            const float* __restrict__ adst, const float* __restrict__ b,
                            float* __restrict__ outx, int N) {
    int gid = blockIdx.x * blockDim.x + threadIdx.x;
    int n = gid >> 6, lane = gid & 63;
    if (n >= N) return;
    int beg = rowp[n], end = rowp[n + 1];
    float4 ad = *(const float4*)(adst + (size_t)n * 4);
    float m0 = -1e30f, m1 = -1e30f, m2 = -1e30f, m3 = -1e30f;
    for (int i = beg + lane; i < end; i += 64) {
        int s = csr[i];
        float4 as = *(const float4*)(asrc + (size_t)s * 4);
        m0 = fmaxf(m0, lrelu(as.x + ad.x));
        m1 = fmaxf(m1, lrelu(as.y + ad.y));
        m2 = fmaxf(m2, lrelu(as.z + ad.z));
        m3 = fmaxf(m3, lrelu(as.w + ad.w));
    }
    #pragma unroll
    for (int off = 32; off; off >>= 1) {
        m0 = fmaxf(m0, __shfl_xor(m0, off));
        m1 = fmaxf(m1, __shfl_xor(m1, off));
        m2 = fmaxf(m2, __shfl_xor(m2, off));
        m3 = fmaxf(m3, __shfl_xor(m3, off));
    }
    float acc0 = 0.f, acc1 = 0.f, acc2 = 0.f, acc3 = 0.f;
    float den0 = 0.f, den1 = 0.f, den2 = 0.f, den3 = 0.f;
    for (int i = beg; i < end; ++i) {
        int s = csr[i];
        float4 as = *(const float4*)(asrc + (size_t)s * 4);
        float w0 = __expf(lrelu(as.x + ad.x) - m0);
        float w1 = __expf(lrelu(as.y + ad.y) - m1);
        float w2 = __expf(lrelu(as.z + ad.z) - m2);
        float w3 = __expf(lrelu(as.w + ad.w) - m3);
        den0 += w0; den1 += w1; den2 += w2; den3 += w3;
        const float* hs = h0 + (size_t)s * 256;
        acc0 += w0 * hs[lane];
        acc1 += w1 * hs[64 + lane];
        acc2 += w2 * hs[128 + lane];
        acc3 += w3 * hs[192 + lane];
    }
    float* po = outx + (size_t)n * 256;
    float v;
    v = acc0 / den0 + b[lane];       po[lane]       = v > 0.f ? v : 0.f;
    v = acc1 / den1 + b[64 + lane];  po[64 + lane]  = v > 0.f ? v : 0.f;
    v = acc2 / den2 + b[128 + lane]; po[128 + lane] = v > 0.f ? v : 0.f;
    v = acc3 / den3 + b[192 + lane]; po[192 + lane] = v > 0.f ? v : 0.f;
}

__global__ void gat_gather1(const int* __restrict__ csr, const int* __restrict__ rowp,
                            const float* __restrict__ h1, const float* __restrict__ asrc,
                            const float* __restrict__ adst, const float* __restrict__ b,
                            float* __restrict__ outx, int N) {
    int gid = blockIdx.x * blockDim.x + threadIdx.x;
    int n = gid >> 6, lane = gid & 63;
    if (n >= N) return;
    int beg = rowp[n], end = rowp[n + 1];
    float adn = adst[n];
    float mx = -1e30f;
    for (int i = beg + lane; i < end; i += 64) {
        int s = csr[i];
        mx = fmaxf(mx, lrelu(asrc[s] + adn));
    }
    #pragma unroll
    for (int off = 32; off; off >>= 1) mx = fmaxf(mx, __shfl_xor(mx, off));
    float acc0 = 0.f, acc1 = 0.f, acc2 = 0.f, acc3 = 0.f, den = 0.f;
    for (int i = beg; i < end; ++i) {
        int s = csr[i];
        float w = __expf(lrelu(asrc[s] + adn) - mx);
        den += w;
        const float* hs = h1 + (size_t)s * 256;
        acc0 += w * hs[lane];
        acc1 += w * hs[64 + lane];
        acc2 += w * hs[128 + lane];
        acc3 += w * hs[192 + lane];
    }
    float inv = 1.f / den;
    float* po = outx + (size_t)n * 256;
    float v;
    v = acc0 * inv + b[lane];       po[lane]       = v > 0.f ? v : 0.f;
    v = acc1 * inv + b[64 + lane];  po[64 + lane]  = v > 0.f ? v : 0.f;
    v = acc2 * inv + b[128 + lane]; po[128 + lane] = v > 0.f ? v : 0.f;
    v = acc3 * inv + b[192 + lane]; po[192 + lane] = v > 0.f ? v : 0.f;
}

// ---------------- weight packing: fp32 [K,Nsrc] -> bf16 MFMA B-fragments ----------------
// out[((kt*NT + nt)*64 + lane)*8 + i] = bf16(W[kt*32 + (lane>>4)*8 + i][nt*16 + (lane&15)])
__global__ void pack_w(const float* __restrict__ W, u16* __restrict__ out,
                       int K, int Nsrc, int NT) {
    int gid  = blockIdx.x * blockDim.x + threadIdx.x;
    int lane = gid & 63, frag = gid >> 6;
    int KT = K >> 5;
    if (frag >= KT * NT) return;
    int nt = frag % NT, kt = frag / NT;
    int n  = nt * 16 + (lane & 15);
    int k0 = kt * 32 + ((lane >> 4) << 3);
    u16x8 v8;
    #pragma unroll
    for (int i = 0; i < 8; ++i) {
        float v = (n < Nsrc) ? W[(size_t)(k0 + i) * Nsrc + n] : 0.f;
        v8[i] = f2bf(v);
    }
    *(u16x8*)(out + (size_t)(frag * 64 + lane) * 8) = v8;
}

// hi/lo split variant (for fp32-accurate GAT GEMMs)
__global__ void pack_w_hl(const float* __restrict__ W, u16* __restrict__ ohi,
                          u16* __restrict__ olo, int K, int Nsrc, int NT) {
    int gid  = blockIdx.x * blockDim.x + threadIdx.x;
    int lane = gid & 63, frag = gid >> 6;
    int KT = K >> 5;
    if (frag >= KT * NT) return;
    int nt = frag % NT, kt = frag / NT;
    int n  = nt * 16 + (lane & 15);
    int k0 = kt * 32 + ((lane >> 4) << 3);
    u16x8 h8, l8;
    #pragma unroll
    for (int i = 0; i < 8; ++i) {
        float v = (n < Nsrc) ? W[(size_t)(k0 + i) * Nsrc + n] : 0.f;
        u16 hi = f2bf(v);
        h8[i] = hi;
        l8[i] = f2bf(v - bf2f(hi));
    }
    *(u16x8*)(ohi + (size_t)(frag * 64 + lane) * 8) = h8;
    *(u16x8*)(olo + (size_t)(frag * 64 + lane) * 8) = l8;
}

// ---------------- shared A-fragment reader (XOR-swizzled LDS) ----------------
__device__ __forceinline__ bf16x8 lds_afrag(const u16* buf, int Kdim, int row0, int kt, int lane) {
    int row = row0 + (lane & 15);
    int k   = kt * 32 + ((lane >> 4) << 3);
    int idx = (row * Kdim + k) ^ ((row & 7) << 3);
    return *(const bf16x8*)(buf + idx);
}

// ---------------- split-bf16 MFMA GEMM: C[M,256] = A[M,K] @ B[K,256], fp32-accurate ----
// 64 rows/block, 512 threads (8 waves); wave w owns cols [32w, 32w+32).
// B pre-packed as hi/lo fragments (NT=16). 3-term split: AhiBhi + AhiBlo + AloBhi.
__global__ __launch_bounds__(512) void gemm_mfma(
    const float* __restrict__ A, const u16* __restrict__ bhi, const u16* __restrict__ blo,
    float* __restrict__ C, int M, int K) {
    __shared__ __align__(16) u16 Ahi[64 * 256];
    __shared__ __align__(16) u16 Alo[64 * 256];
    int t = threadIdx.x, lane = t & 63, w = t >> 6;
    int row0 = blockIdx.x * 64;
    int K4 = K >> 2;

    // stage A -> hi/lo bf16 LDS planes (swizzled)
    for (int idx = t; idx < 64 * K4; idx += 512) {
        int row = idx / K4, kq = (idx % K4) << 2;
        int gr = row0 + row;
        float4 v = make_float4(0.f, 0.f, 0.f, 0.f);
        if (gr < M) v = *(const float4*)(A + (size_t)gr * K + kq);
        u16x4 h4, l4;
        float vv[4] = {v.x, v.y, v.z, v.w};
        #pragma unroll
        for (int i = 0; i < 4; ++i) {
            u16 hi = f2bf(vv[i]);
            h4[i] = hi;
            l4[i] = f2bf(vv[i] - bf2f(hi));
        }
        int sidx = (row * K + kq) ^ ((row & 7) << 3);
        *(u16x4*)(Ahi + sidx) = h4;
        *(u16x4*)(Alo + sidx) = l4;
    }
    __syncthreads();

    int KT = K >> 5;
    f32x4 acc[4][2] = {};
    for (int kt = 0; kt < KT; ++kt) {
        bf16x8 ah[4], al[4];
        #pragma unroll
        for (int mt = 0; mt < 4; ++mt) {
            ah[mt] = lds_afrag(Ahi, K, mt * 16, kt, lane);
            al[mt] = lds_afrag(Alo, K, mt * 16, kt, lane);
        }
        #pragma unroll
        for (int nt = 0; nt < 2; ++nt) {
            int ntg = w * 2 + nt;
            size_t fo = ((size_t)(kt * 16 + ntg) * 64 + lane) * 8;
            bf16x8 bh = *(const bf16x8*)(bhi + fo);
            bf16x8 bl = *(const bf16x8*)(blo + fo);
            #pragma unroll
            for (int mt = 0; mt < 4; ++mt) {
                acc[mt][nt] = __builtin_amdgcn_mfma_f32_16x16x32_bf16(al[mt], bh, acc[mt][nt], 0, 0, 0);
                acc[mt][nt] = __builtin_amdgcn_mfma_f32_16x16x32_bf16(ah[mt], bl, acc[mt][nt], 0, 0, 0);
                acc[mt][nt] = __builtin_amdgcn_mfma_f32_16x16x32_bf16(ah[mt], bh, acc[mt][nt], 0, 0, 0);
            }
        }
    }

    #pragma unroll
    for (int mt = 0; mt < 4; ++mt)
        #pragma unroll
        for (int nt = 0; nt < 2; ++nt) {
            int col = w * 32 + nt * 16 + (lane & 15);
            #pragma unroll
            for (int j = 0; j < 4; ++j) {
                int gr = row0 + mt * 16 + ((lane >> 4) << 2) + j;
                if (gr < M) C[(size_t)gr * 256 + col] = acc[mt][nt][j];
            }
        }
}

// ---------------- fused MLP via bf16 MFMA: 256 -> 512 -> 1024 -> 10 -> softmax ----------------
#define NB 32

__global__ __launch_bounds__(512) void mlp_mfma(
    const float* __restrict__ m0,
    const u16* __restrict__ w1p, const float* __restrict__ lb1,
    const u16* __restrict__ w2p, const float* __restrict__ lb2,
    const u16* __restrict__ w3p, const float* __restrict__ lb3,
    float* __restrict__ out, int N) {
    __shared__ __align__(16) u16 ldsA0[32 * 256];
    __shared__ __align__(16) u16 ldsA1[32 * 512];
    __shared__ __align__(16) u16 ldsA2[32 * 1024];
    __shared__ float slog[32 * 16];

    int t = threadIdx.x, lane = t & 63, w = t >> 6;
    int nb = blockIdx.x * NB;

    slog[t] = 0.f;

    #pragma unroll
    for (int u = 0; u < 2; ++u) {
        int unit = t + u * 512;
        int row = unit >> 5, kb = (unit & 31) << 3;
        int gn = nb + row;
        u16x8 v8;
        if (gn < N) {
            const float* p = m0 + (size_t)gn * 256 + kb;
            #pragma unroll
            for (int i = 0; i < 8; ++i) v8[i] = f2bf(p[i]);
        } else {
            v8 = (u16x8)0;
        }
        int idx = (row * 256 + kb) ^ ((row & 7) << 3);
        *(u16x8*)(ldsA0 + idx) = v8;
    }
    __syncthreads();

    // ---- layer 1 ----
    {
        f32x4 acc[2][4] = {};
        for (int kt = 0; kt < 8; ++kt) {
            bf16x8 a0 = lds_afrag(ldsA0, 256, 0,  kt, lane);
            bf16x8 a1 = lds_afrag(ldsA0, 256, 16, kt, lane);
            #pragma unroll
            for (int nt = 0; nt < 4; ++nt) {
                int ntg = w * 4 + nt;
                bf16x8 b = *(const bf16x8*)(w1p + ((size_t)(kt * 32 + ntg) * 64 + lane) * 8);
                acc[0][nt] = __builtin_amdgcn_mfma_f32_16x16x32_bf16(a0, b, acc[0][nt], 0, 0, 0);
                acc[1][nt] = __builtin_amdgcn_mfma_f32_16x16x32_bf16(a1, b, acc[1][nt], 0, 0, 0);
            }
        }
        #pragma unroll
        for (int mt = 0; mt < 2; ++mt)
            #pragma unroll
            for (int nt = 0; nt < 4; ++nt) {
                int col = w * 64 + nt * 16 + (lane & 15);
                float bv = lb1[col];
                #pragma unroll
                for (int j = 0; j < 4; ++j) {
                    int row = mt * 16 + ((lane >> 4) << 2) + j;
                    float v = acc[mt][nt][j] + bv;
                    v = v > 0.f ? v : 0.f;
                    ldsA1[(row * 512 + col) ^ ((row & 7) << 3)] = f2bf(v);
                }
            }
    }
    __syncthreads();

    // ---- layer 2 ----
    {
        f32x4 acc[2][8] = {};
        for (int kt = 0; kt < 16; ++kt) {
            bf16x8 a0 = lds_afrag(ldsA1, 512, 0,  kt, lane);
            bf16x8 a1 = lds_afrag(ldsA1, 512, 16, kt, lane);
            #pragma unroll
            for (int nt = 0; nt < 8; ++nt) {
                int ntg = w * 8 + nt;
                bf16x8 b = *(const bf16x8*)(w2p + ((size_t)(kt * 64 + ntg) * 64 + lane) * 8);
                acc[0][nt] = __builtin_amdgcn_mfma_f32_16x16x32_bf16(a0, b, acc[0][nt], 0, 0, 0);
                acc[1][nt] = __builtin_amdgcn_mfma_f32_16x16x32_bf16(a1, b, acc[1][nt], 0, 0, 0);
            }
        }
        #pragma unroll
        for (int mt = 0; mt < 2; ++mt)
            #pragma unroll
            for (int nt = 0; nt < 8; ++nt) {
                int col = w * 128 + nt * 16 + (lane & 15);
                float bv = lb2[col];
                #pragma unroll
                for (int j = 0; j < 4; ++j) {
                    int row = mt * 16 + ((lane >> 4) << 2) + j;
                    float v = acc[mt][nt][j] + bv;
                    v = v > 0.f ? v : 0.f;
                    ldsA2[(row * 1024 + col) ^ ((row & 7) << 3)] = f2bf(v);
                }
            }
    }
    __syncthreads();

    // ---- layer 3 ----
    {
        f32x4 acc[2] = {};
        #pragma unroll
        for (int kk = 0; kk < 4; ++kk) {
            int kt = w * 4 + kk;
            bf16x8 a0 = lds_afrag(ldsA2, 1024, 0,  kt, lane);
            bf16x8 a1 = lds_afrag(ldsA2, 1024, 16, kt, lane);
            bf16x8 b  = *(const bf16x8*)(w3p + ((size_t)kt * 64 + lane) * 8);
            acc[0] = __builtin_amdgcn_mfma_f32_16x16x32_bf16(a0, b, acc[0], 0, 0, 0);
            acc[1] = __builtin_amdgcn_mfma_f32_16x16x32_bf16(a1, b, acc[1], 0, 0, 0);
        }
        int col = lane & 15;
        #pragma unroll
        for (int mt = 0; mt < 2; ++mt)
            #pragma unroll
            for (int j = 0; j < 4; ++j) {
                int row = mt * 16 + ((lane >> 4) << 2) + j;
                atomicAdd(&slog[row * 16 + col], acc[mt][j]);
            }
    }
    __syncthreads();

    if (t < 32) {
        int gn = nb + t;
        if (gn < N) {
            float lg[10], m = -1e30f;
            #pragma unroll
            for (int k = 0; k < 10; ++k) {
                float v = slog[t * 16 + k] + lb3[k];
                v = v > 0.f ? v : 0.f;
                lg[k] = v;
                if (v > m) m = v;
            }
            float ssum = 0.f;
            #pragma unroll
            for (int k = 0; k < 10; ++k) { lg[k] = __expf(lg[k] - m); ssum += lg[k]; }
            float inv = 1.f / ssum;
            #pragma unroll
            for (int k = 0; k < 10; ++k) out[(size_t)gn * 10 + k] = lg[k] * inv;
        }
    }
}

// ---------------------------------------------------------------------------
extern "C" void kernel_launch(void* const* d_in, const int* in_sizes, int n_in,
                              void* d_out, int out_size, void* d_ws, size_t ws_size,
                              hipStream_t stream) {
    const float* x       = (const float*)d_in[0];
    const int*   ei      = (const int*)  d_in[1];
    const float* W0      = (const float*)d_in[2];
    const float* a_src0  = (const float*)d_in[3];
    const float* a_dst0  = (const float*)d_in[4];
    const float* b0      = (const float*)d_in[5];
    const float* W1      = (const float*)d_in[6];
    const float* a_src1  = (const float*)d_in[7];
    const float* a_dst1  = (const float*)d_in[8];
    const float* b1      = (const float*)d_in[9];
    const float* lw1     = (const float*)d_in[10];
    const float* lb1     = (const float*)d_in[11];
    const float* lw2     = (const float*)d_in[12];
    const float* lb2     = (const float*)d_in[13];
    const float* lw3     = (const float*)d_in[14];
    const float* lb3     = (const float*)d_in[15];
    float*       out     = (float*)d_out;

    const int N  = in_sizes[0] / F_IN;   // 50000
    const int E  = in_sizes[1] / 2;      // 400000
    const int ET = E + N;

    // workspace layout
    float* ws   = (float*)d_ws;
    size_t szH  = (size_t)N * 256;
    float* bufH = ws;                         // h0 / h1
    float* bufG = ws + szH;                   // x1 / m0
    float* asrc = ws + 2 * szH;               // N*4 (layer0) or N (layer1)
    float* adst = asrc + (size_t)N * 4;       // N*4
    u16*   w1p  = (u16*)(adst + (size_t)N * 4);          // 256*512
    u16*   w2p  = w1p + 256 * 512;                       // 512*1024
    u16*   w3p  = w2p + 512 * 1024;                      // 1024*16
    u16*   w0h  = w3p + 1024 * 16;                       // 128*256 hi
    u16*   w0l  = w0h + 128 * 256;                       // 128*256 lo
    u16*   w1h  = w0l + 128 * 256;                       // 256*256 hi
    u16*   w1l  = w1h + 256 * 256;                       // 256*256 lo
    int*   deg  = (int*)(w1l + 256 * 256);
    int*   rowp   = deg + N;                  // N+1
    int*   cursor = rowp + N + 1;
    int*   part   = cursor + N;
    int*   bsum   = part + N;                 // 256
    int*   csr    = bsum + 256;               // ET

    const int TB  = 256;
    const int nb1 = (N + 255) / 256;
    const int gemm_grid = (N + 63) / 64;

    // ===== pack weights =====
    pack_w<<<(8  * 32 * 64 + TB - 1) / TB, TB, 0, stream>>>(lw1, w1p, 256,  512,  32);
    pack_w<<<(16 * 64 * 64 + TB - 1) / TB, TB, 0, stream>>>(lw2, w2p, 512,  1024, 64);
    pack_w<<<(32 * 1  * 64 + TB - 1) / TB, TB, 0, stream>>>(lw3, w3p, 1024, 10,   1);
    pack_w_hl<<<(4 * 16 * 64 + TB - 1) / TB, TB, 0, stream>>>(W0, w0h, w0l, 128, 256, 16);
    pack_w_hl<<<(8 * 16 * 64 + TB - 1) / TB, TB, 0, stream>>>(W1, w1h, w1l, 256, 256, 16);

    // ===== build CSR (dst-sorted; valid edges + self-loops) =====
    deg_init<<<nb1, TB, 0, stream>>>(deg, N);
    count_deg<<<(E + TB - 1) / TB, TB, 0, stream>>>(ei, deg, E);
    scan1<<<nb1, TB, 0, stream>>>(deg, part, bsum, N);
    scan2<<<1, TB, 0, stream>>>(bsum, nb1);
    scan3<<<nb1, TB, 0, stream>>>(deg, part, bsum, rowp, cursor, N);
    scatter_k<<<(ET + TB - 1) / TB, TB, 0, stream>>>(ei, cursor, csr, E, N);

    // ===== GAT layer 0 =====
    gemm_mfma<<<gemm_grid, 512, 0, stream>>>(x, w0h, w0l, bufH, N, 128);
    alphas0_k<<<(N * 64 + TB - 1) / TB, TB, 0, stream>>>(bufH, a_src0, a_dst0, asrc, adst, N);
    gat_gather0<<<((size_t)N * 64 + TB - 1) / TB, TB, 0, stream>>>(csr, rowp, bufH, asrc, adst, b0, bufG, N);

    // ===== GAT layer 1 =====
    gemm_mfma<<<gemm_grid, 512, 0, stream>>>(bufG, w1h, w1l, bufH, N, 256);
    alphas1_k<<<(N * 64 + TB - 1) / TB, TB, 0, stream>>>(bufH, a_src1, a_dst1, asrc, adst, N);
    gat_gather1<<<((size_t)N * 64 + TB - 1) / TB, TB, 0, stream>>>(csr, rowp, bufH, asrc, adst, b1, bufG, N);

    // ===== fused MLP head (bf16 MFMA) + softmax =====
    mlp_mfma<<<(N + NB - 1) / NB, 512, 0, stream>>>(bufG, w1p, lb1, w2p, lb2, w3p, lb3, out, N);
}